// Round 4
// baseline (9553.395 us; speedup 1.0000x reference)
//
#include <hip/hip_runtime.h>
#include <math.h>

using floatx4 = __attribute__((ext_vector_type(4))) float;
using bf16x8  = __attribute__((ext_vector_type(8))) __bf16;
using ushort8 = __attribute__((ext_vector_type(8))) unsigned short;

// ---------- scalar helpers ----------
__device__ __forceinline__ float b2f(unsigned short u) {
  unsigned v = ((unsigned)u) << 16; float f; __builtin_memcpy(&f, &v, 4); return f;
}
__device__ __forceinline__ unsigned short f2b(float f) {
  unsigned u; __builtin_memcpy(&u, &f, 4);
  u += 0x7fffu + ((u >> 16) & 1u);          // RNE
  return (unsigned short)(u >> 16);
}
__device__ __forceinline__ float gelu_f(float x) {
  return 0.5f * x * (1.0f + erff(x * 0.7071067811865475f));
}
__device__ __forceinline__ float gelu_d(float x) {
  float cdf = 0.5f * (1.0f + erff(x * 0.7071067811865475f));
  float pdf = 0.3989422804014327f * expf(-0.5f * x * x);
  return cdf + x * pdf;
}
__device__ __forceinline__ void gload16(const unsigned short* g, unsigned short* l) {
  __builtin_amdgcn_global_load_lds(
      (__attribute__((address_space(1))) void*)(g),
      (__attribute__((address_space(3))) void*)(l), 16, 0, 0);
}

// ---------- GEMM: C[M,N] = A[M,K] * Bt[N,K]^T  (128x128 tiles) ----------
// MODE 0: +bias all rows, bf16 out            (context GEMMs, weight-combine)
// MODE 1: +bias all rows, gelu, bf16 out      (Wc1)
// MODE 2: +bias even rows (+bias2), bf16 out  (input GEMM)
// MODE 3: +bias even rows, gelu-JVP pairs     (Wm1, Wp1)
template<int MODE>
__global__ __launch_bounds__(256) void gemm_bt_k(
    const unsigned short* __restrict__ A, const unsigned short* __restrict__ Bt,
    void* __restrict__ C, const float* __restrict__ bias,
    const float* __restrict__ bias2, int M, int N, int K)
{
  __shared__ unsigned short As[128 * 32];
  __shared__ unsigned short Bs[128 * 32];
  const int tid  = threadIdx.x;
  const int lane = tid & 63;
  const int wave = tid >> 6;
  const int row0 = blockIdx.y * 128;
  const int col0 = blockIdx.x * 128;

  const int sr = wave * 32 + (lane >> 2);
  const int sk = (lane & 3) * 8;
  const unsigned short* Ag0 = A  + (size_t)(row0 + sr) * K + sk;
  const unsigned short* Ag1 = Ag0 + (size_t)16 * K;
  const unsigned short* Bg0 = Bt + (size_t)(col0 + sr) * K + sk;
  const unsigned short* Bg1 = Bg0 + (size_t)16 * K;
  unsigned short* As0 = &As[wave * 1024];
  unsigned short* Bs0 = &Bs[wave * 1024];

  const int wr = wave >> 1, wc = wave & 1;
  const int mrow = lane & 15;
  const int kq = (lane >> 4) * 8;

  floatx4 acc[4][4];
  const floatx4 zf4 = {0.f, 0.f, 0.f, 0.f};
  #pragma unroll
  for (int i = 0; i < 4; i++)
    #pragma unroll
    for (int j = 0; j < 4; j++) acc[i][j] = zf4;

  for (int k0 = 0; k0 < K; k0 += 32) {
    __syncthreads();
    gload16(Ag0 + k0, As0);
    gload16(Ag1 + k0, As0 + 512);
    gload16(Bg0 + k0, Bs0);
    gload16(Bg1 + k0, Bs0 + 512);
    __syncthreads();
    bf16x8 af[4], bfr[4];
    #pragma unroll
    for (int t = 0; t < 4; t++)
      af[t] = *(const bf16x8*)&As[(wr * 64 + t * 16 + mrow) * 32 + kq];
    #pragma unroll
    for (int t = 0; t < 4; t++)
      bfr[t] = *(const bf16x8*)&Bs[(wc * 64 + t * 16 + mrow) * 32 + kq];
    #pragma unroll
    for (int i = 0; i < 4; i++)
      #pragma unroll
      for (int j = 0; j < 4; j++)
        acc[i][j] = __builtin_amdgcn_mfma_f32_16x16x32_bf16(af[i], bfr[j], acc[i][j], 0, 0, 0);
  }

  const int quad = lane >> 4;
  const int cl = lane & 15;
  #pragma unroll
  for (int j = 0; j < 4; j++) {
    int col = col0 + wc * 64 + j * 16 + cl;
    float bb = bias ? bias[col] : 0.f;
    if (MODE >= 2) { if (bias2) bb += bias2[col]; }
    #pragma unroll
    for (int i = 0; i < 4; i++) {
      int rbase = row0 + wr * 64 + i * 16 + quad * 4;   // rbase % 4 == 0
      if (MODE == 3) {
        #pragma unroll
        for (int pp = 0; pp < 2; pp++) {
          float p = acc[i][j][2 * pp] + bb;        // primal (even row)
          float t = acc[i][j][2 * pp + 1];         // tangent (odd row)
          ((unsigned short*)C)[(size_t)(rbase + 2 * pp) * N + col]     = f2b(gelu_f(p));
          ((unsigned short*)C)[(size_t)(rbase + 2 * pp + 1) * N + col] = f2b(gelu_d(p) * t);
        }
      } else {
        #pragma unroll
        for (int rr = 0; rr < 4; rr++) {
          int row = rbase + rr;
          float v = acc[i][j][rr];
          if (MODE == 0 || MODE == 1) v += bb;
          if (MODE == 2) { if ((row & 1) == 0) v += bb; }
          if (MODE == 1) v = gelu_f(v);
          ((unsigned short*)C)[(size_t)row * N + col] = f2b(v);
        }
      }
    }
  }
}

// ---------- fused GEMM + residual + LN-JVP (+xatt), in-place on h ----------
// Tile: 32 rows x 512 cols (full H) per block, 4 waves (each 32x128 = 2x8 tiles).
// Block owns complete rows -> LN sums are block-local (shfl + LDS reduce).
// In-place safe: block reads only its own 32 A/h rows, writes same rows.
template<bool XATT>
__global__ __launch_bounds__(256) void gemm_ln_k(
    const unsigned short* __restrict__ A, const unsigned short* __restrict__ Bt,
    unsigned short* __restrict__ h, const float* __restrict__ bias,
    const float* __restrict__ g, const float* __restrict__ be,
    const unsigned short* __restrict__ xatt, const float* __restrict__ sc_p,
    int K)
{
  constexpr int N = 512;
  __shared__ unsigned short As[32 * 32];     // 2 KB
  __shared__ unsigned short Bs[512 * 32];    // 32 KB
  __shared__ unsigned short Hs[32 * 512];    // 32 KB residual rows
  __shared__ float red[16][4][4];            // [pair][wave][sum]
  const int tid = threadIdx.x, lane = tid & 63, wave = tid >> 6;
  const int row0 = blockIdx.x * 32;

  // stage residual rows (completes by first in-loop barrier)
  #pragma unroll
  for (int t = 0; t < 8; t++) {
    int r = wave * 8 + t;
    gload16(h + (size_t)(row0 + r) * N + lane * 8, &Hs[r * N]);
  }

  const int srb = lane >> 2;
  const int sk  = (lane & 3) * 8;
  const int mrow = lane & 15, kq = (lane >> 4) * 8;

  floatx4 acc[2][8];
  const floatx4 zf4 = {0.f, 0.f, 0.f, 0.f};
  #pragma unroll
  for (int i = 0; i < 2; i++)
    #pragma unroll
    for (int j = 0; j < 8; j++) acc[i][j] = zf4;

  for (int k0 = 0; k0 < K; k0 += 32) {
    __syncthreads();
    if (wave < 2)
      gload16(A + (size_t)(row0 + wave * 16 + srb) * K + k0 + sk, &As[wave * 512]);
    #pragma unroll
    for (int t = 0; t < 8; t++) {
      int n = wave * 128 + t * 16;
      gload16(Bt + (size_t)(n + srb) * K + k0 + sk, &Bs[n * 32]);
    }
    __syncthreads();
    bf16x8 af[2], bfr[8];
    #pragma unroll
    for (int i = 0; i < 2; i++)
      af[i] = *(const bf16x8*)&As[(i * 16 + mrow) * 32 + kq];
    #pragma unroll
    for (int j = 0; j < 8; j++)
      bfr[j] = *(const bf16x8*)&Bs[(wave * 128 + j * 16 + mrow) * 32 + kq];
    #pragma unroll
    for (int i = 0; i < 2; i++)
      #pragma unroll
      for (int j = 0; j < 8; j++)
        acc[i][j] = __builtin_amdgcn_mfma_f32_16x16x32_bf16(af[i], bfr[j], acc[i][j], 0, 0, 0);
  }

  const int quad = lane >> 4, cl = lane & 15;
  float bc[8], gc[8], bec[8];
  #pragma unroll
  for (int j = 0; j < 8; j++) {
    int col = wave * 128 + j * 16 + cl;
    bc[j] = bias[col]; gc[j] = g[col]; bec[j] = be[col];
  }

  // per-pair partial sums over this wave's 128 cols (all 4 sums are linear)
  #pragma unroll
  for (int i = 0; i < 2; i++) {
    #pragma unroll
    for (int rp = 0; rp < 2; rp++) {
      int re = i * 16 + quad * 4 + rp * 2;
      float sx = 0.f, sxx = 0.f, sdv = 0.f, sxdv = 0.f;
      #pragma unroll
      for (int j = 0; j < 8; j++) {
        int col = wave * 128 + j * 16 + cl;
        float xp = acc[i][j][rp * 2]     + bc[j] + b2f(Hs[re * N + col]);
        float dv = acc[i][j][rp * 2 + 1]         + b2f(Hs[(re + 1) * N + col]);
        sx += xp; sxx += xp * xp; sdv += dv; sxdv += xp * dv;
      }
      #pragma unroll
      for (int off = 1; off <= 8; off <<= 1) {
        sx   += __shfl_xor(sx, off, 64);
        sxx  += __shfl_xor(sxx, off, 64);
        sdv  += __shfl_xor(sdv, off, 64);
        sxdv += __shfl_xor(sxdv, off, 64);
      }
      if (cl == 0) {
        int pr = i * 8 + quad * 2 + rp;
        red[pr][wave][0] = sx; red[pr][wave][1] = sxx;
        red[pr][wave][2] = sdv; red[pr][wave][3] = sxdv;
      }
    }
  }
  __syncthreads();

  const float inv = 1.0f / 512.0f;
  float sl = 0.f;
  if (XATT) sl = *sc_p;
  #pragma unroll
  for (int i = 0; i < 2; i++) {
    #pragma unroll
    for (int rp = 0; rp < 2; rp++) {
      int pr = i * 8 + quad * 2 + rp;
      float sx   = red[pr][0][0] + red[pr][1][0] + red[pr][2][0] + red[pr][3][0];
      float sxx  = red[pr][0][1] + red[pr][1][1] + red[pr][2][1] + red[pr][3][1];
      float sdv  = red[pr][0][2] + red[pr][1][2] + red[pr][2][2] + red[pr][3][2];
      float sxdv = red[pr][0][3] + red[pr][1][3] + red[pr][2][3] + red[pr][3][3];
      float m = sx * inv;
      float var = sxx * inv - m * m;
      float rstd = rsqrtf(var + 1e-5f);
      float dm = sdv * inv;
      float cm = (sxdv - m * sdv) * inv * rstd;   // mean(xhat*dv)
      int re = i * 16 + quad * 4 + rp * 2;
      size_t growe = (size_t)(row0 + re);
      #pragma unroll
      for (int j = 0; j < 8; j++) {
        int col = wave * 128 + j * 16 + cl;
        float xp = acc[i][j][rp * 2]     + bc[j] + b2f(Hs[re * N + col]);
        float dv = acc[i][j][rp * 2 + 1]         + b2f(Hs[(re + 1) * N + col]);
        float xh = (xp - m) * rstd;
        float y = xh * gc[j] + bec[j];
        if (XATT) y += sl * b2f(xatt[(growe >> 1) * N + col]);
        float dy = gc[j] * rstd * (dv - dm - xh * cm);
        h[growe * N + col]       = f2b(y);
        h[(growe + 1) * N + col] = f2b(dy);
      }
    }
  }
}

// ---------- fused Wp2 GEMM + Euler update + Hutchinson + Abuf build ----------
// N=128 == full output row per 128x128 block (grid = M/128 blocks).
__global__ __launch_bounds__(256) void gemm_vout_k(
    const unsigned short* __restrict__ A, const unsigned short* __restrict__ Bt,
    const float* __restrict__ bias, const float* __restrict__ u_cur,
    const float* __restrict__ u_next, float* __restrict__ zf,
    float* __restrict__ ldb, unsigned short* __restrict__ Abuf,
    int K, float dtv)
{
  constexpr int N = 128;
  __shared__ unsigned short As[128 * 32];
  __shared__ unsigned short Bs[128 * 32];
  __shared__ float red[64][2];
  const int tid = threadIdx.x, lane = tid & 63, wave = tid >> 6;
  const int row0 = blockIdx.x * 128;

  const int sr = wave * 32 + (lane >> 2);
  const int sk = (lane & 3) * 8;
  const unsigned short* Ag0 = A  + (size_t)(row0 + sr) * K + sk;
  const unsigned short* Ag1 = Ag0 + (size_t)16 * K;
  const unsigned short* Bg0 = Bt + (size_t)sr * K + sk;
  const unsigned short* Bg1 = Bg0 + (size_t)16 * K;
  unsigned short* As0 = &As[wave * 1024];
  unsigned short* Bs0 = &Bs[wave * 1024];

  const int wr = wave >> 1, wc = wave & 1;
  const int mrow = lane & 15, kq = (lane >> 4) * 8;

  floatx4 acc[4][4];
  const floatx4 zf4 = {0.f, 0.f, 0.f, 0.f};
  #pragma unroll
  for (int i = 0; i < 4; i++)
    #pragma unroll
    for (int j = 0; j < 4; j++) acc[i][j] = zf4;

  for (int k0 = 0; k0 < K; k0 += 32) {
    __syncthreads();
    gload16(Ag0 + k0, As0);
    gload16(Ag1 + k0, As0 + 512);
    gload16(Bg0 + k0, Bs0);
    gload16(Bg1 + k0, Bs0 + 512);
    __syncthreads();
    bf16x8 af[4], bfr[4];
    #pragma unroll
    for (int t = 0; t < 4; t++)
      af[t] = *(const bf16x8*)&As[(wr * 64 + t * 16 + mrow) * 32 + kq];
    #pragma unroll
    for (int t = 0; t < 4; t++)
      bfr[t] = *(const bf16x8*)&Bs[(wc * 64 + t * 16 + mrow) * 32 + kq];
    #pragma unroll
    for (int i = 0; i < 4; i++)
      #pragma unroll
      for (int j = 0; j < 4; j++)
        acc[i][j] = __builtin_amdgcn_mfma_f32_16x16x32_bf16(af[i], bfr[j], acc[i][j], 0, 0, 0);
  }

  const int quad = lane >> 4, cl = lane & 15;
  #pragma unroll
  for (int i = 0; i < 4; i++) {
    #pragma unroll
    for (int rp = 0; rp < 2; rp++) {
      int rloc_e = wr * 64 + i * 16 + quad * 4 + rp * 2;
      size_t growe = (size_t)(row0 + rloc_e);
      size_t b = growe >> 1;
      float dacc = 0.f;
      #pragma unroll
      for (int j = 0; j < 4; j++) {
        int col = wc * 64 + j * 16 + cl;
        float v  = acc[i][j][rp * 2] + bias[col];
        float Ju = acc[i][j][rp * 2 + 1];
        float z = zf[b * N + col] + v * dtv;
        zf[b * N + col] = z;
        Abuf[growe * N + col] = f2b(z);
        if (u_next) Abuf[(growe + 1) * N + col] = f2b(u_next[b * N + col]);
        dacc += u_cur[b * N + col] * Ju;
      }
      #pragma unroll
      for (int off = 1; off <= 8; off <<= 1) dacc += __shfl_xor(dacc, off, 64);
      if (cl == 0) red[wr * 32 + i * 8 + quad * 2 + rp][wc] = dacc;
    }
  }
  __syncthreads();
  if (tid < 64) ldb[(row0 >> 1) + tid] += (red[tid][0] + red[tid][1]) * dtv;
}

// ---------- transpose+cast: W[K,N] f32 -> Wt[N,K] bf16 (batched over z) ----------
__global__ void transpose_cast_k(const float* __restrict__ W,
                                 unsigned short* __restrict__ Wt, int K, int N)
{
  __shared__ float tile[32][33];
  size_t off = (size_t)blockIdx.z * K * N;
  const float* Wp = W + off;
  unsigned short* Wtp = Wt + off;
  int bx = blockIdx.x, by = blockIdx.y;
  int tx = threadIdx.x, ty = threadIdx.y;
  #pragma unroll
  for (int i = ty; i < 32; i += 8)
    tile[i][tx] = Wp[(size_t)(by * 32 + i) * N + bx * 32 + tx];
  __syncthreads();
  #pragma unroll
  for (int i = ty; i < 32; i += 8)
    Wtp[(size_t)(bx * 32 + i) * K + by * 32 + tx] = f2b(tile[tx][i]);
}

// ---------- combined bias: bout[l][out] = sum_k bv[l][k]*Wb[l][k,out] + bo[l][out] ----------
__global__ __launch_bounds__(256) void combine_bias_k(
    const float* __restrict__ bvp, const float* __restrict__ Wb,
    const float* __restrict__ bo, float* __restrict__ bout, int H)
{
  int out = blockIdx.x * blockDim.x + threadIdx.x;
  int l   = blockIdx.y;
  const float* A2 = Wb + (size_t)l * H * H;
  float s = bo[(size_t)l * H + out];
  for (int k = 0; k < H; k++) s += bvp[(size_t)l * H + k] * A2[(size_t)k * H + out];
  bout[(size_t)l * H + out] = s;
}

// ---------- f32 -> bf16 cast ----------
__global__ __launch_bounds__(256) void cast_k(const float* __restrict__ in,
                                              unsigned short* __restrict__ out, size_t n) {
  size_t i = blockIdx.x * blockDim.x + threadIdx.x;
  if (i < n) out[i] = f2b(in[i]);
}

// ---------- all S time embeddings: tvecs[s][H] ----------
__global__ __launch_bounds__(512) void temb_all_k(
    const float* __restrict__ Wt1, const float* __restrict__ bt1,
    const float* __restrict__ Wt2, const float* __restrict__ bt2,
    float dtv, float* __restrict__ tvecs, int H)
{
  __shared__ float e[512];
  int j = threadIdx.x;
  float t = fminf(fmaxf((float)blockIdx.x * dtv, 0.f), 1.f);
  e[j] = gelu_f(t * Wt1[j] + bt1[j]);
  __syncthreads();
  float s = bt2[j];
  for (int k = 0; k < H; k++) s += e[k] * Wt2[(size_t)k * H + j];
  tvecs[(size_t)blockIdx.x * H + j] = s;
}

// ---------- init: zf=x, ld=0, Abuf interleaved [z;u] ----------
__global__ __launch_bounds__(256) void init_k(
    const float* __restrict__ x, const float* __restrict__ u0,
    float* __restrict__ zf, float* __restrict__ ld,
    unsigned short* __restrict__ Abuf, int BF, int Bsz, int F)
{
  int i = (int)(blockIdx.x * blockDim.x + threadIdx.x);
  if (i < BF) {
    int r = i / F, c = i - r * F;
    float v = x[i];
    zf[i] = v;
    Abuf[(size_t)(2 * r) * F + c]     = f2b(v);
    Abuf[(size_t)(2 * r + 1) * F + c] = f2b(u0[i]);
  }
  if (i < Bsz) ld[i] = 0.f;
}

// ---------- write outputs ----------
__global__ __launch_bounds__(256) void final_k(
    const float* __restrict__ zf, const float* __restrict__ ld,
    float* __restrict__ out, int BF, int Bsz)
{
  int i = (int)(blockIdx.x * blockDim.x + threadIdx.x);
  if (i < BF) out[i] = zf[i];
  if (i < Bsz) out[BF + i] = ld[i];
}

extern "C" void kernel_launch(void* const* d_in, const int* in_sizes, int n_in,
                              void* d_out, int out_size, void* d_ws, size_t ws_size,
                              hipStream_t stream) {
  constexpr int B = 8192, F = 128, C = 256, H = 512, L = 4, S = 10;
  constexpr int B2 = 2 * B;
  constexpr int BF = B * F;
  const float dtv = 1.0f / S;

  const float* x    = (const float*)d_in[0];
  const float* ctxI = (const float*)d_in[1];
  const float* u    = (const float*)d_in[2];
  const float* Wi   = (const float*)d_in[3];
  const float* bi   = (const float*)d_in[4];
  const float* Wt1  = (const float*)d_in[5];
  const float* bt1  = (const float*)d_in[6];
  const float* Wt2  = (const float*)d_in[7];
  const float* bt2  = (const float*)d_in[8];
  const float* Wc1  = (const float*)d_in[9];
  const float* bc1  = (const float*)d_in[10];
  const float* Wc2  = (const float*)d_in[11];
  const float* bc2  = (const float*)d_in[12];
  const float* Wv   = (const float*)d_in[13];
  const float* bv   = (const float*)d_in[14];
  const float* Woa  = (const float*)d_in[15];
  const float* boa  = (const float*)d_in[16];
  const float* g1   = (const float*)d_in[17];
  const float* be1  = (const float*)d_in[18];
  const float* Wm1  = (const float*)d_in[19];
  const float* bm1  = (const float*)d_in[20];
  const float* Wm2  = (const float*)d_in[21];
  const float* bm2  = (const float*)d_in[22];
  const float* g2   = (const float*)d_in[23];
  const float* be2  = (const float*)d_in[24];
  const float* Wcv  = (const float*)d_in[25];
  const float* bcv  = (const float*)d_in[26];
  const float* Wco  = (const float*)d_in[27];
  const float* bco  = (const float*)d_in[28];
  const float* scal = (const float*)d_in[29];
  const float* Wp1  = (const float*)d_in[30];
  const float* bp1  = (const float*)d_in[31];
  const float* Wp2  = (const float*)d_in[32];
  const float* bp2  = (const float*)d_in[33];

  // ---- workspace layout ----
  char* wp = (char*)d_ws;
  auto alloc = [&](size_t bytes) -> void* {
    void* r = (void*)wp;
    wp += (bytes + 255) & ~(size_t)255;
    return r;
  };
  unsigned short* wWit  = (unsigned short*)alloc((size_t)H * F * 2);
  unsigned short* wWc1t = (unsigned short*)alloc((size_t)2 * H * C * 2);
  unsigned short* wWc2t = (unsigned short*)alloc((size_t)H * 2 * H * 2);
  unsigned short* wWvoT = (unsigned short*)alloc((size_t)L * H * H * 2);  // combined Wv@Woa, [out,in]
  unsigned short* wCtxT = (unsigned short*)alloc((size_t)L * H * H * 2);  // combined Wcv@Wco
  unsigned short* wWm1t = (unsigned short*)alloc((size_t)L * 4 * H * H * 2);
  unsigned short* wWm2t = (unsigned short*)alloc((size_t)L * H * 4 * H * 2);
  unsigned short* wWp1t = (unsigned short*)alloc((size_t)H * H * 2);
  unsigned short* wWp2t = (unsigned short*)alloc((size_t)F * H * 2);
  unsigned short* wOaT  = (unsigned short*)alloc((size_t)L * H * H * 2);
  unsigned short* wCoT  = (unsigned short*)alloc((size_t)L * H * H * 2);
  unsigned short* wVb   = (unsigned short*)alloc((size_t)L * H * H * 2);
  unsigned short* wCvb  = (unsigned short*)alloc((size_t)L * H * H * 2);
  float* bvo            = (float*)alloc((size_t)L * H * 4);
  float* cbvo           = (float*)alloc((size_t)L * H * 4);
  float* tvecs          = (float*)alloc((size_t)S * H * 4);
  unsigned short* ctxc  = (unsigned short*)alloc((size_t)B * C * 2);
  unsigned short* Abuf  = (unsigned short*)alloc((size_t)B2 * F * 2);
  unsigned short* hbuf  = (unsigned short*)alloc((size_t)B2 * H * 2);
  unsigned short* tmp2  = (unsigned short*)alloc((size_t)B2 * H * 2);
  unsigned short* mbuf  = (unsigned short*)alloc((size_t)B2 * 4 * H * 2);
  unsigned short* xattb = (unsigned short*)alloc((size_t)L * B * H * 2);
  float* zf             = (float*)alloc((size_t)B * F * 4);
  float* ldb            = (float*)alloc((size_t)B * 4);
  (void)ws_size; (void)in_sizes; (void)n_in; (void)out_size;

  auto T = [&](const float* W, unsigned short* Wt, int K, int N, int Lz) {
    dim3 g(N / 32, K / 32, Lz);
    transpose_cast_k<<<g, dim3(32, 8), 0, stream>>>(W, Wt, K, N);
  };
  auto G = [&](int mode, const unsigned short* A, const unsigned short* Bt, void* Cc,
               const float* bias, const float* bias2, int M, int N, int K) {
    dim3 g(N / 128, M / 128);
    switch (mode) {
      case 0: gemm_bt_k<0><<<g, 256, 0, stream>>>(A, Bt, Cc, bias, bias2, M, N, K); break;
      case 1: gemm_bt_k<1><<<g, 256, 0, stream>>>(A, Bt, Cc, bias, bias2, M, N, K); break;
      case 2: gemm_bt_k<2><<<g, 256, 0, stream>>>(A, Bt, Cc, bias, bias2, M, N, K); break;
      case 3: gemm_bt_k<3><<<g, 256, 0, stream>>>(A, Bt, Cc, bias, bias2, M, N, K); break;
    }
  };

  // ---- weight prep ----
  T(Wi,  wWit,  F, H, 1);
  T(Wc1, wWc1t, C, 2 * H, 1);
  T(Wc2, wWc2t, 2 * H, H, 1);
  T(Wm1, wWm1t, H, 4 * H, L);
  T(Wm2, wWm2t, 4 * H, H, L);
  T(Wp1, wWp1t, H, H, 1);
  T(Wp2, wWp2t, H, F, 1);
  // combined attn weight via MFMA GEMM: wWvoT[out,in] = sum_k Woa^T[out,k]*Wv[in,k]
  T(Woa, wOaT, H, H, L);
  T(Wco, wCoT, H, H, L);
  cast_k<<<((size_t)L * H * H + 255) / 256, 256, 0, stream>>>(Wv,  wVb,  (size_t)L * H * H);
  cast_k<<<((size_t)L * H * H + 255) / 256, 256, 0, stream>>>(Wcv, wCvb, (size_t)L * H * H);
  for (int l = 0; l < L; l++) {
    size_t o2 = (size_t)l * H * H;
    G(0, wOaT + o2, wVb  + o2, wWvoT + o2, nullptr, nullptr, H, H, H);
    G(0, wCoT + o2, wCvb + o2, wCtxT + o2, nullptr, nullptr, H, H, H);
  }
  combine_bias_k<<<dim3(H / 256, L), 256, 0, stream>>>(bv,  Woa, boa, bvo,  H);
  combine_bias_k<<<dim3(H / 256, L), 256, 0, stream>>>(bcv, Wco, bco, cbvo, H);

  // ---- context path (z-independent): xatt[l] = ctx @ (Wcv@Wco) + (bcv@Wco+bco) ----
  cast_k<<<(B * C + 255) / 256, 256, 0, stream>>>(ctxI, ctxc, (size_t)B * C);
  G(1, ctxc, wWc1t, mbuf, bc1, nullptr, B, 2 * H, C);           // gelu fused
  G(0, mbuf, wWc2t, tmp2, bc2, nullptr, B, H, 2 * H);
  for (int l = 0; l < L; l++)
    G(0, tmp2, wCtxT + (size_t)l * H * H, xattb + (size_t)l * B * H,
      cbvo + l * H, nullptr, B, H, H);

  temb_all_k<<<S, H, 0, stream>>>(Wt1, bt1, Wt2, bt2, dtv, tvecs, H);
  init_k<<<(BF + 255) / 256, 256, 0, stream>>>(x, u, zf, ldb, Abuf, BF, B, F);

  // ---- S Euler steps; rows interleaved (2i primal, 2i+1 tangent) ----
  for (int s = 0; s < S; s++) {
    G(2, Abuf, wWit, hbuf, bi, tvecs + (size_t)s * H, B2, H, F);
    for (int l = 0; l < L; l++) {
      size_t o2 = (size_t)l * H * H;
      size_t om = (size_t)l * 4 * H * H;
      gemm_ln_k<false><<<B2 / 32, 256, 0, stream>>>(
          hbuf, wWvoT + o2, hbuf, bvo + l * H, g1 + l * H, be1 + l * H,
          nullptr, nullptr, H);
      G(3, hbuf, wWm1t + om, mbuf, bm1 + (size_t)l * 4 * H, nullptr, B2, 4 * H, H);
      gemm_ln_k<true><<<B2 / 32, 256, 0, stream>>>(
          mbuf, wWm2t + om, hbuf, bm2 + l * H, g2 + l * H, be2 + l * H,
          xattb + (size_t)l * B * H, scal + l, 4 * H);
    }
    G(3, hbuf, wWp1t, tmp2, bp1, nullptr, B2, H, H);
    const float* u_cur = u + (size_t)s * BF;
    const float* u_next = (s + 1 < S) ? u + (size_t)(s + 1) * BF : nullptr;
    gemm_vout_k<<<B2 / 128, 256, 0, stream>>>(
        tmp2, wWp2t, bp2, u_cur, u_next, zf, ldb, Abuf, H, dtv);
  }

  final_k<<<(BF + 255) / 256, 256, 0, stream>>>(zf, ldb, (float*)d_out, BF, B);
}